// Round 1
// baseline (1971.054 us; speedup 1.0000x reference)
//
#include <hip/hip_runtime.h>
#include <math.h>

#define H_SIZE   4096
#define N_HEADS  32
#define N_KV     8
#define HEAD_DIM 128
#define GROUP    4
#define Q_SIZE   4096
#define KV_SIZE  1024
#define QKV_OUT  6144          // Q_SIZE + 2*KV_SIZE
#define NUM_SEQS 64
#define MAX_CTX  2048
#define BLK_SZ   16
#define BLOCKS_PER_SEQ 128
#define ATT_SCALE 0.08838834764831845f   // 128^-0.5

// ---------------- GEMM: Y[s][j] = dot(X[s][:K], W[j][:K]) ----------------
// One block = 256 threads = 4 waves; each wave computes 8 consecutive j.
__global__ __launch_bounds__(256)
void gemm_rowdot(const float* __restrict__ X, const float* __restrict__ W,
                 float* __restrict__ Y, int K, int N) {
    const int jb_per_s = N / 32;
    const int s  = blockIdx.x / jb_per_s;
    const int jb = blockIdx.x % jb_per_s;
    const int wave = threadIdx.x >> 6;
    const int lane = threadIdx.x & 63;
    const int j0 = jb * 32 + wave * 8;
    const float* xrow = X + (size_t)s * K;

    float acc[8] = {0.f,0.f,0.f,0.f,0.f,0.f,0.f,0.f};
    for (int k = lane * 4; k < K; k += 256) {
        float4 x = *(const float4*)(xrow + k);
        #pragma unroll
        for (int jj = 0; jj < 8; ++jj) {
            float4 w = *(const float4*)(W + (size_t)(j0 + jj) * K + k);
            acc[jj] += x.x*w.x + x.y*w.y + x.z*w.z + x.w*w.w;
        }
    }
    #pragma unroll
    for (int jj = 0; jj < 8; ++jj) {
        float v = acc[jj];
        #pragma unroll
        for (int off = 32; off; off >>= 1) v += __shfl_down(v, off);
        if (lane == 0) Y[(size_t)s * N + j0 + jj] = v;
    }
}

// ---------------- RoPE (in-place on qkv workspace) ----------------
// grid (NUM_SEQS, 40): head 0..31 = q heads, 32..39 = k heads. 64 threads.
__global__ void rope_kernel(float* __restrict__ qkv, const int* __restrict__ positions) {
    const int s    = blockIdx.x;
    const int head = blockIdx.y;
    const int i    = threadIdx.x;         // 0..63 (half = 64)
    float* base = qkv + (size_t)s * QKV_OUT +
                  (head < N_HEADS ? head * HEAD_DIM
                                  : Q_SIZE + (head - N_HEADS) * HEAD_DIM);
    const float pos = (float)positions[s];
    const float inv_freq = powf(10000.0f, -(float)i / 64.0f);
    const float ang = pos * inv_freq;
    const float c = cosf(ang), sn = sinf(ang);
    const float x1 = base[i], x2 = base[i + 64];
    base[i]      = x1 * c - x2 * sn;
    base[i + 64] = x2 * c + x1 * sn;
}

// ---------------- Paged GQA decode attention ----------------
// One block (256 thr = 4 waves) per (seq, kv_head). GROUP=4 q-heads.
__global__ __launch_bounds__(256)
void attn_kernel(const float* __restrict__ qkv,
                 const float* __restrict__ k_cache,
                 const float* __restrict__ v_cache,
                 const int*   __restrict__ block_tables,
                 const int*   __restrict__ context_lens,
                 float* __restrict__ attn_out) {
    const int s = blockIdx.x >> 3;
    const int h = blockIdx.x & 7;
    const int ctx = context_lens[s];
    const int pos = ctx - 1;

    __shared__ float sc[GROUP][MAX_CTX];      // 32 KB scores
    __shared__ float qs[GROUP][HEAD_DIM];     // 2 KB
    __shared__ float red[4][GROUP][HEAD_DIM]; // 8 KB partial PV
    __shared__ float rsum[GROUP];

    const int tid  = threadIdx.x;
    const int wave = tid >> 6;
    const int lane = tid & 63;

    // load the 4 rope'd q vectors for this kv group
    for (int idx = tid; idx < GROUP * HEAD_DIM; idx += 256) {
        int g = idx >> 7, d = idx & 127;
        qs[g][d] = qkv[(size_t)s * QKV_OUT + (h * GROUP + g) * HEAD_DIM + d];
    }
    __syncthreads();

    const int* bt = block_tables + s * BLOCKS_PER_SEQ;
    const float* knew = qkv + (size_t)s * QKV_OUT + Q_SIZE + h * HEAD_DIM;
    const float* vnew = qkv + (size_t)s * QKV_OUT + Q_SIZE + KV_SIZE + h * HEAD_DIM;

    // ---- scores: each wave handles tokens t ≡ wave (mod 4) ----
    for (int t = wave; t < ctx; t += 4) {
        const float* kp;
        if (t == pos) kp = knew;
        else {
            int blk = bt[t >> 4];
            kp = k_cache + (((size_t)blk * BLK_SZ + (t & 15)) * N_KV + h) * HEAD_DIM;
        }
        float2 kv = *(const float2*)(kp + lane * 2);
        float p0 = kv.x * qs[0][lane*2] + kv.y * qs[0][lane*2+1];
        float p1 = kv.x * qs[1][lane*2] + kv.y * qs[1][lane*2+1];
        float p2 = kv.x * qs[2][lane*2] + kv.y * qs[2][lane*2+1];
        float p3 = kv.x * qs[3][lane*2] + kv.y * qs[3][lane*2+1];
        #pragma unroll
        for (int off = 32; off; off >>= 1) {
            p0 += __shfl_xor(p0, off);
            p1 += __shfl_xor(p1, off);
            p2 += __shfl_xor(p2, off);
            p3 += __shfl_xor(p3, off);
        }
        if (lane == 0) {
            sc[0][t] = p0 * ATT_SCALE;
            sc[1][t] = p1 * ATT_SCALE;
            sc[2][t] = p2 * ATT_SCALE;
            sc[3][t] = p3 * ATT_SCALE;
        }
    }
    __syncthreads();

    // ---- softmax: wave g handles head g ----
    {
        const int g = wave;   // GROUP == 4 waves
        float m = -1e30f;
        for (int t = lane; t < ctx; t += 64) m = fmaxf(m, sc[g][t]);
        #pragma unroll
        for (int off = 32; off; off >>= 1) m = fmaxf(m, __shfl_xor(m, off));
        float sum = 0.f;
        for (int t = lane; t < ctx; t += 64) {
            float e = __expf(sc[g][t] - m);
            sc[g][t] = e;
            sum += e;
        }
        #pragma unroll
        for (int off = 32; off; off >>= 1) sum += __shfl_xor(sum, off);
        if (lane == 0) rsum[g] = 1.0f / sum;
    }
    __syncthreads();

    // ---- PV: each wave handles tokens t ≡ wave (mod 4), all 4 heads ----
    float ax[GROUP] = {0.f,0.f,0.f,0.f};
    float ay[GROUP] = {0.f,0.f,0.f,0.f};
    for (int t = wave; t < ctx; t += 4) {
        const float* vp;
        if (t == pos) vp = vnew;
        else {
            int blk = bt[t >> 4];
            vp = v_cache + (((size_t)blk * BLK_SZ + (t & 15)) * N_KV + h) * HEAD_DIM;
        }
        float2 vv = *(const float2*)(vp + lane * 2);
        #pragma unroll
        for (int g = 0; g < GROUP; ++g) {
            float p = sc[g][t];
            ax[g] += p * vv.x;
            ay[g] += p * vv.y;
        }
    }
    #pragma unroll
    for (int g = 0; g < GROUP; ++g) {
        red[wave][g][lane*2]   = ax[g];
        red[wave][g][lane*2+1] = ay[g];
    }
    __syncthreads();

    // ---- cross-wave reduce + write: wave g owns head g ----
    {
        const int g = wave;
        const float r = rsum[g];
        float o0 = (red[0][g][lane*2]   + red[1][g][lane*2] +
                    red[2][g][lane*2]   + red[3][g][lane*2]) * r;
        float o1 = (red[0][g][lane*2+1] + red[1][g][lane*2+1] +
                    red[2][g][lane*2+1] + red[3][g][lane*2+1]) * r;
        float* op = attn_out + (size_t)s * Q_SIZE + (h * GROUP + g) * HEAD_DIM;
        op[lane*2]   = o0;
        op[lane*2+1] = o1;
    }
}

extern "C" void kernel_launch(void* const* d_in, const int* in_sizes, int n_in,
                              void* d_out, int out_size, void* d_ws, size_t ws_size,
                              hipStream_t stream) {
    const int*   positions    = (const int*)  d_in[0];
    const float* hidden       = (const float*)d_in[1];
    const float* k_cache      = (const float*)d_in[2];
    const float* v_cache      = (const float*)d_in[3];
    const int*   block_tables = (const int*)  d_in[4];
    const int*   context_lens = (const int*)  d_in[5];
    const float* W_qkv        = (const float*)d_in[6];
    const float* W_o          = (const float*)d_in[7];
    float* out = (float*)d_out;

    float* qkv_ws  = (float*)d_ws;                                  // 64*6144 floats
    float* attn_ws = qkv_ws + (size_t)NUM_SEQS * QKV_OUT;           // 64*4096 floats

    // 1) QKV projection
    gemm_rowdot<<<NUM_SEQS * (QKV_OUT / 32), 256, 0, stream>>>(
        hidden, W_qkv, qkv_ws, H_SIZE, QKV_OUT);
    // 2) RoPE on q (32 heads) and k (8 heads)
    rope_kernel<<<dim3(NUM_SEQS, N_HEADS + N_KV), 64, 0, stream>>>(qkv_ws, positions);
    // 3) paged GQA attention
    attn_kernel<<<NUM_SEQS * N_KV, 256, 0, stream>>>(
        qkv_ws, k_cache, v_cache, block_tables, context_lens, attn_ws);
    // 4) output projection
    gemm_rowdot<<<NUM_SEQS * (Q_SIZE / 32), 256, 0, stream>>>(
        attn_ws, W_o, out, H_SIZE, Q_SIZE);
}

// Round 2
// 364.654 us; speedup vs baseline: 5.4053x; 5.4053x over previous
//
#include <hip/hip_runtime.h>
#include <math.h>

#define H_SIZE   4096
#define N_HEADS  32
#define N_KV     8
#define HEAD_DIM 128
#define GROUP    4
#define Q_SIZE   4096
#define KV_SIZE  1024
#define QKV_OUT  6144          // Q_SIZE + 2*KV_SIZE
#define NUM_SEQS 64
#define MAX_CTX  2048
#define BLK_SZ   16
#define BLOCKS_PER_SEQ 128
#define ATT_SCALE 0.08838834764831845f   // 128^-0.5

#define CHUNK    256
#define NCHUNK   8             // MAX_CTX / CHUNK
#define KSPLIT   4
#define KCHUNK   1024          // H_SIZE / KSPLIT

// ---------------- Tiled GEMM: Y[64][N] = X[64][4096] @ W[N][4096]^T ----------------
// grid (N/64, KSPLIT); block 256 thr; 64x64 output tile, 4x4 per-thread micro-tile.
// Writes K-split partials Yp[c][64][N] (deterministic; reduced by reduce_ksplit).
__global__ __launch_bounds__(256)
void gemm_tiled(const float* __restrict__ X, const float* __restrict__ W,
                float* __restrict__ Yp, int N) {
    const int n0 = blockIdx.x * 64;
    const int k0 = blockIdx.y * KCHUNK;
    __shared__ float Xs[64][33];   // [m][k] +1 pad -> conflict-free column reads
    __shared__ float Ws[64][33];   // [n][k]
    const int tid = threadIdx.x;
    const int tx  = tid & 15;      // n quad
    const int ty  = tid >> 4;      // m quad
    float acc[4][4] = {};

    for (int kb = k0; kb < k0 + KCHUNK; kb += 32) {
        #pragma unroll
        for (int r = 0; r < 2; ++r) {
            int p   = tid + r * 256;       // 0..511 float4 slots
            int row = p >> 3;              // 64 rows
            int c4  = (p & 7) * 4;         // 8 float4 per row (32 floats)
            float4 xv = *(const float4*)(X + (size_t)row * H_SIZE + kb + c4);
            float4 wv = *(const float4*)(W + (size_t)(n0 + row) * H_SIZE + kb + c4);
            Xs[row][c4+0] = xv.x; Xs[row][c4+1] = xv.y; Xs[row][c4+2] = xv.z; Xs[row][c4+3] = xv.w;
            Ws[row][c4+0] = wv.x; Ws[row][c4+1] = wv.y; Ws[row][c4+2] = wv.z; Ws[row][c4+3] = wv.w;
        }
        __syncthreads();
        #pragma unroll
        for (int kk = 0; kk < 32; ++kk) {
            float a[4], b[4];
            #pragma unroll
            for (int i = 0; i < 4; ++i) a[i] = Xs[ty*4+i][kk];
            #pragma unroll
            for (int j = 0; j < 4; ++j) b[j] = Ws[tx*4+j][kk];
            #pragma unroll
            for (int i = 0; i < 4; ++i)
                #pragma unroll
                for (int j = 0; j < 4; ++j)
                    acc[i][j] = fmaf(a[i], b[j], acc[i][j]);
        }
        __syncthreads();
    }

    float* yp = Yp + (size_t)blockIdx.y * 64 * N;
    #pragma unroll
    for (int i = 0; i < 4; ++i) {
        float4 v = make_float4(acc[i][0], acc[i][1], acc[i][2], acc[i][3]);
        *(float4*)(yp + (size_t)(ty*4+i) * N + n0 + tx*4) = v;
    }
}

__global__ __launch_bounds__(256)
void reduce_ksplit(const float* __restrict__ Yp, float* __restrict__ Y, int total) {
    int i = blockIdx.x * 256 + threadIdx.x;
    if (i >= total) return;
    float s = 0.f;
    #pragma unroll
    for (int c = 0; c < KSPLIT; ++c) s += Yp[(size_t)c * total + i];
    Y[i] = s;
}

// ---------------- RoPE (in-place on qkv workspace) ----------------
__global__ void rope_kernel(float* __restrict__ qkv, const int* __restrict__ positions) {
    const int s    = blockIdx.x;
    const int head = blockIdx.y;
    const int i    = threadIdx.x;         // 0..63
    float* base = qkv + (size_t)s * QKV_OUT +
                  (head < N_HEADS ? head * HEAD_DIM
                                  : Q_SIZE + (head - N_HEADS) * HEAD_DIM);
    const float pos = (float)positions[s];
    const float inv_freq = powf(10000.0f, -(float)i / 64.0f);
    const float ang = pos * inv_freq;
    const float c = cosf(ang), sn = sinf(ang);
    const float x1 = base[i], x2 = base[i + 64];
    base[i]      = x1 * c - x2 * sn;
    base[i + 64] = x2 * c + x1 * sn;
}

// ---------------- Flash-decode attention: per-chunk partials ----------------
// grid (NUM_SEQS*N_KV, NCHUNK); block 256 thr = 4 waves.
// Phase 1: lane-per-token score streaming (no shuffles).
// Phase 2: coalesced PV with LDS-broadcast probs.
__global__ __launch_bounds__(256)
void attn_chunk(const float* __restrict__ qkv,
                const float* __restrict__ k_cache,
                const float* __restrict__ v_cache,
                const int*   __restrict__ block_tables,
                const int*   __restrict__ context_lens,
                float* __restrict__ pacc,   // [sh][c][g][128] unnormalized sum e*v
                float* __restrict__ pml) {  // [sh][c][g][2] = {m, l}
    const int sh = blockIdx.x;
    const int s  = sh >> 3;
    const int h  = sh & 7;
    const int c  = blockIdx.y;
    const int ctx = context_lens[s];
    if (c * CHUNK >= ctx) return;
    const int pos = ctx - 1;
    const int nvalid = min(CHUNK, ctx - c * CHUNK);

    __shared__ float qs[GROUP][HEAD_DIM];   // 2 KB
    __shared__ float sc[GROUP][CHUNK];      // 4 KB scores -> probs
    __shared__ float red[4][GROUP][HEAD_DIM]; // 8 KB
    __shared__ float mls[GROUP][2];

    const int tid  = threadIdx.x;
    const int wave = tid >> 6;
    const int lane = tid & 63;

    for (int idx = tid; idx < GROUP * HEAD_DIM; idx += 256) {
        int g = idx >> 7, d = idx & 127;
        qs[g][d] = qkv[(size_t)s * QKV_OUT + (h * GROUP + g) * HEAD_DIM + d];
    }
    __syncthreads();

    const int*   bt   = block_tables + s * BLOCKS_PER_SEQ;
    const float* knew = qkv + (size_t)s * QKV_OUT + Q_SIZE + h * HEAD_DIM;
    const float* vnew = qkv + (size_t)s * QKV_OUT + Q_SIZE + KV_SIZE + h * HEAD_DIM;

    // ---- phase 1: one token per lane (t always < MAX_CTX -> loads always safe) ----
    {
        const int t = c * CHUNK + tid;
        const float* kp;
        if (t == pos) kp = knew;
        else {
            int blk = bt[t >> 4];
            kp = k_cache + ((size_t)(blk * BLK_SZ + (t & 15)) * N_KV + h) * HEAD_DIM;
        }
        float s0 = 0.f, s1 = 0.f, s2 = 0.f, s3 = 0.f;
        #pragma unroll 8
        for (int d4 = 0; d4 < 32; ++d4) {
            float4 kv = *(const float4*)(kp + d4 * 4);
            float4 q0 = *(const float4*)(&qs[0][d4 * 4]);
            float4 q1 = *(const float4*)(&qs[1][d4 * 4]);
            float4 q2 = *(const float4*)(&qs[2][d4 * 4]);
            float4 q3 = *(const float4*)(&qs[3][d4 * 4]);
            s0 = fmaf(kv.x,q0.x, fmaf(kv.y,q0.y, fmaf(kv.z,q0.z, fmaf(kv.w,q0.w, s0))));
            s1 = fmaf(kv.x,q1.x, fmaf(kv.y,q1.y, fmaf(kv.z,q1.z, fmaf(kv.w,q1.w, s1))));
            s2 = fmaf(kv.x,q2.x, fmaf(kv.y,q2.y, fmaf(kv.z,q2.z, fmaf(kv.w,q2.w, s2))));
            s3 = fmaf(kv.x,q3.x, fmaf(kv.y,q3.y, fmaf(kv.z,q3.z, fmaf(kv.w,q3.w, s3))));
        }
        if (tid < nvalid) {
            sc[0][tid] = s0 * ATT_SCALE; sc[1][tid] = s1 * ATT_SCALE;
            sc[2][tid] = s2 * ATT_SCALE; sc[3][tid] = s3 * ATT_SCALE;
        } else {
            sc[0][tid] = -1e30f; sc[1][tid] = -1e30f;
            sc[2][tid] = -1e30f; sc[3][tid] = -1e30f;
        }
    }
    __syncthreads();

    // ---- chunk-local softmax: wave g owns head g ----
    {
        const int g = wave;
        float m = -1e30f;
        #pragma unroll
        for (int r = 0; r < 4; ++r) m = fmaxf(m, sc[g][lane + r * 64]);
        #pragma unroll
        for (int off = 32; off; off >>= 1) m = fmaxf(m, __shfl_xor(m, off));
        float l = 0.f;
        #pragma unroll
        for (int r = 0; r < 4; ++r) {
            float e = __expf(sc[g][lane + r * 64] - m);
            sc[g][lane + r * 64] = e;
            l += e;
        }
        #pragma unroll
        for (int off = 32; off; off >>= 1) l += __shfl_xor(l, off);
        if (lane == 0) { mls[g][0] = m; mls[g][1] = l; }
    }
    __syncthreads();

    // ---- phase 2: PV, wave handles 64 consecutive tokens, coalesced V ----
    float2 acc[GROUP] = {};
    int cnt = nvalid - wave * 64;
    if (cnt > 64) cnt = 64;
    for (int ii = 0; ii < cnt; ++ii) {
        const int i = wave * 64 + ii;
        const int t = c * CHUNK + i;
        const float* vp;
        if (t == pos) vp = vnew;
        else {
            int blk = bt[t >> 4];
            vp = v_cache + ((size_t)(blk * BLK_SZ + (t & 15)) * N_KV + h) * HEAD_DIM;
        }
        float2 vv = *(const float2*)(vp + lane * 2);
        #pragma unroll
        for (int g = 0; g < GROUP; ++g) {
            float p = sc[g][i];
            acc[g].x = fmaf(p, vv.x, acc[g].x);
            acc[g].y = fmaf(p, vv.y, acc[g].y);
        }
    }
    #pragma unroll
    for (int g = 0; g < GROUP; ++g) {
        red[wave][g][lane*2]   = acc[g].x;
        red[wave][g][lane*2+1] = acc[g].y;
    }
    __syncthreads();

    {
        const int g = wave;
        float ox = red[0][g][lane*2]   + red[1][g][lane*2]   + red[2][g][lane*2]   + red[3][g][lane*2];
        float oy = red[0][g][lane*2+1] + red[1][g][lane*2+1] + red[2][g][lane*2+1] + red[3][g][lane*2+1];
        size_t idx = ((size_t)sh * NCHUNK + c) * GROUP + g;
        pacc[idx * HEAD_DIM + lane*2]     = ox;
        pacc[idx * HEAD_DIM + lane*2 + 1] = oy;
        if (lane == 0) { pml[idx*2] = mls[g][0]; pml[idx*2+1] = mls[g][1]; }
    }
}

// ---------------- combine chunk partials ----------------
// grid (NUM_SEQS*N_KV); 256 thr; wave g owns head g.
__global__ __launch_bounds__(256)
void attn_reduce(const float* __restrict__ pacc, const float* __restrict__ pml,
                 const int* __restrict__ context_lens, float* __restrict__ out) {
    const int sh = blockIdx.x;
    const int s  = sh >> 3;
    const int h  = sh & 7;
    const int g    = threadIdx.x >> 6;
    const int lane = threadIdx.x & 63;
    const int ctx = context_lens[s];
    const int nc  = (ctx + CHUNK - 1) / CHUNK;

    float M = -1e30f;
    for (int cc = 0; cc < nc; ++cc)
        M = fmaxf(M, pml[(((size_t)sh * NCHUNK + cc) * GROUP + g) * 2]);
    float ox = 0.f, oy = 0.f, L = 0.f;
    for (int cc = 0; cc < nc; ++cc) {
        size_t idx = ((size_t)sh * NCHUNK + cc) * GROUP + g;
        float w = __expf(pml[idx*2] - M);
        L = fmaf(w, pml[idx*2+1], L);
        float2 pa = *(const float2*)(pacc + idx * HEAD_DIM + lane*2);
        ox = fmaf(w, pa.x, ox);
        oy = fmaf(w, pa.y, oy);
    }
    float inv = 1.0f / L;
    float* op = out + (size_t)s * Q_SIZE + (h * GROUP + g) * HEAD_DIM;
    op[lane*2]     = ox * inv;
    op[lane*2 + 1] = oy * inv;
}

extern "C" void kernel_launch(void* const* d_in, const int* in_sizes, int n_in,
                              void* d_out, int out_size, void* d_ws, size_t ws_size,
                              hipStream_t stream) {
    const int*   positions    = (const int*)  d_in[0];
    const float* hidden       = (const float*)d_in[1];
    const float* k_cache      = (const float*)d_in[2];
    const float* v_cache      = (const float*)d_in[3];
    const int*   block_tables = (const int*)  d_in[4];
    const int*   context_lens = (const int*)  d_in[5];
    const float* W_qkv        = (const float*)d_in[6];
    const float* W_o          = (const float*)d_in[7];
    float* out = (float*)d_out;

    float* qkv_ws  = (float*)d_ws;                                   // 393216 f
    float* attn_ws = qkv_ws + (size_t)NUM_SEQS * QKV_OUT;            // 262144 f
    float* scratch = attn_ws + (size_t)NUM_SEQS * Q_SIZE;            // shared region
    // scratch uses: QKV partials (4*393216 f), then attn pacc/pml, then Wo partials
    float* pacc = scratch;                                            // 2097152 f
    float* pml  = scratch + (size_t)NUM_SEQS * N_KV * NCHUNK * GROUP * HEAD_DIM; // 32768 f

    // 1) QKV projection (K-split partials + reduce)
    gemm_tiled<<<dim3(QKV_OUT / 64, KSPLIT), 256, 0, stream>>>(hidden, W_qkv, scratch, QKV_OUT);
    reduce_ksplit<<<(NUM_SEQS * QKV_OUT + 255) / 256, 256, 0, stream>>>(scratch, qkv_ws, NUM_SEQS * QKV_OUT);
    // 2) RoPE
    rope_kernel<<<dim3(NUM_SEQS, N_HEADS + N_KV), 64, 0, stream>>>(qkv_ws, positions);
    // 3) flash-decode attention
    attn_chunk<<<dim3(NUM_SEQS * N_KV, NCHUNK), 256, 0, stream>>>(
        qkv_ws, k_cache, v_cache, block_tables, context_lens, pacc, pml);
    attn_reduce<<<NUM_SEQS * N_KV, 256, 0, stream>>>(pacc, pml, context_lens, attn_ws);
    // 4) output projection
    gemm_tiled<<<dim3(Q_SIZE / 64, KSPLIT), 256, 0, stream>>>(attn_ws, W_o, scratch, Q_SIZE);
    reduce_ksplit<<<(NUM_SEQS * Q_SIZE + 255) / 256, 256, 0, stream>>>(scratch, out, NUM_SEQS * Q_SIZE);
}

// Round 3
// 287.597 us; speedup vs baseline: 6.8535x; 1.2679x over previous
//
#include <hip/hip_runtime.h>
#include <math.h>

#define H_SIZE   4096
#define N_HEADS  32
#define N_KV     8
#define HEAD_DIM 128
#define GROUP    4
#define Q_SIZE   4096
#define KV_SIZE  1024
#define QKV_OUT  6144          // Q_SIZE + 2*KV_SIZE
#define NUM_SEQS 64
#define MAX_CTX  2048
#define BLK_SZ   16
#define BLOCKS_PER_SEQ 128
#define ATT_SCALE 0.08838834764831845f   // 128^-0.5

#define CHUNK    256
#define NCHUNK   8             // MAX_CTX / CHUNK
#define KSPLIT   8
#define KCHUNK   512           // H_SIZE / KSPLIT

typedef __attribute__((ext_vector_type(8))) short bf16x8;
typedef __attribute__((ext_vector_type(4))) float f32x4;

__device__ __forceinline__ short f2bf(float f) {
    unsigned u = __builtin_bit_cast(unsigned, f);
    unsigned r = (u + 0x7fffu + ((u >> 16) & 1u)) >> 16;   // RNE
    return (short)r;
}

__device__ __forceinline__ bf16x8 load_cvt8(const float* p) {
    float4 a = *(const float4*)p;
    float4 b = *(const float4*)(p + 4);
    bf16x8 r;
    r[0]=f2bf(a.x); r[1]=f2bf(a.y); r[2]=f2bf(a.z); r[3]=f2bf(a.w);
    r[4]=f2bf(b.x); r[5]=f2bf(b.y); r[6]=f2bf(b.z); r[7]=f2bf(b.w);
    return r;
}

// ---------------- MFMA GEMM: Yp[c][64][N] = X[64][4096(chunk c)] @ W[N][.]^T ----------
// grid (N/64, KSPLIT); block 256 = 4 waves. Wave w owns cols n0+w*16..+15, all 64 rows.
// A (X) is L2-hot (1 MB); B (W) streamed from HBM exactly once; both cvt to bf16 in regs.
__global__ __launch_bounds__(256)
void gemm_mfma(const float* __restrict__ X, const float* __restrict__ W,
               float* __restrict__ Yp, int N) {
    const int n0   = blockIdx.x * 64;
    const int k0   = blockIdx.y * KCHUNK;
    const int wave = threadIdx.x >> 6;
    const int lane = threadIdx.x & 63;
    const int ncol = n0 + wave * 16 + (lane & 15);
    const int klane = (lane >> 4) * 8;     // A/B frag: k = klane + e (e=0..7)

    const float* wrow  = W + (size_t)ncol * H_SIZE + k0 + klane;
    const float* xbase = X + (size_t)(lane & 15) * H_SIZE + k0 + klane;

    f32x4 acc[4] = {};
    for (int k = 0; k < KCHUNK; k += 32) {
        bf16x8 bf = load_cvt8(wrow + k);
        #pragma unroll
        for (int m = 0; m < 4; ++m) {
            bf16x8 af = load_cvt8(xbase + (size_t)m * 16 * H_SIZE + k);
            acc[m] = __builtin_amdgcn_mfma_f32_16x16x32_bf16(af, bf, acc[m], 0, 0, 0);
        }
    }
    // D layout: row = m*16 + 4*(lane>>4)+j, col = ncol
    float* yp = Yp + (size_t)blockIdx.y * 64 * N;
    #pragma unroll
    for (int m = 0; m < 4; ++m)
        #pragma unroll
        for (int j = 0; j < 4; ++j)
            yp[(size_t)(m * 16 + (lane >> 4) * 4 + j) * N + ncol] = acc[m][j];
}

// ---------------- fused K-split reduce + RoPE for the QKV output ----------------
// grid (NUM_SEQS, 14); block 256. idx<2560: rope pair (40 heads x 64 pairs); else v copy.
__global__ __launch_bounds__(256)
void qkv_reduce_rope(const float* __restrict__ Yp, float* __restrict__ qkv,
                     const int* __restrict__ positions) {
    const int s   = blockIdx.x;
    const int idx = blockIdx.y * 256 + threadIdx.x;
    const float pos = (float)positions[s];
    if (idx < 2560) {
        const int head = idx >> 6, d = idx & 63;
        const int j1 = (head < N_HEADS ? head * HEAD_DIM
                                       : Q_SIZE + (head - N_HEADS) * HEAD_DIM) + d;
        const int j2 = j1 + 64;
        float x1 = 0.f, x2 = 0.f;
        #pragma unroll
        for (int c = 0; c < KSPLIT; ++c) {
            x1 += Yp[((size_t)c * 64 + s) * QKV_OUT + j1];
            x2 += Yp[((size_t)c * 64 + s) * QKV_OUT + j2];
        }
        const float inv_freq = powf(10000.0f, -(float)d / 64.0f);
        const float ang = pos * inv_freq;
        const float cs = cosf(ang), sn = sinf(ang);
        qkv[(size_t)s * QKV_OUT + j1] = x1 * cs - x2 * sn;
        qkv[(size_t)s * QKV_OUT + j2] = x2 * cs + x1 * sn;
    } else if (idx < 3584) {
        const int j = Q_SIZE + KV_SIZE + (idx - 2560);
        float v = 0.f;
        #pragma unroll
        for (int c = 0; c < KSPLIT; ++c)
            v += Yp[((size_t)c * 64 + s) * QKV_OUT + j];
        qkv[(size_t)s * QKV_OUT + j] = v;
    }
}

__global__ __launch_bounds__(256)
void reduce_ksplit(const float* __restrict__ Yp, float* __restrict__ Y, int total) {
    int i = blockIdx.x * 256 + threadIdx.x;
    if (i >= total) return;
    float s = 0.f;
    #pragma unroll
    for (int c = 0; c < KSPLIT; ++c) s += Yp[(size_t)c * total + i];
    Y[i] = s;
}

// ---------------- Flash-decode attention: per-chunk partials ----------------
__global__ __launch_bounds__(256)
void attn_chunk(const float* __restrict__ qkv,
                const float* __restrict__ k_cache,
                const float* __restrict__ v_cache,
                const int*   __restrict__ block_tables,
                const int*   __restrict__ context_lens,
                float* __restrict__ pacc,   // [sh][c][g][128] unnormalized sum e*v
                float* __restrict__ pml) {  // [sh][c][g][2] = {m, l}
    const int sh = blockIdx.x;
    const int s  = sh >> 3;
    const int h  = sh & 7;
    const int c  = blockIdx.y;
    const int ctx = context_lens[s];
    if (c * CHUNK >= ctx) return;
    const int pos = ctx - 1;
    const int nvalid = min(CHUNK, ctx - c * CHUNK);

    __shared__ float qs[GROUP][HEAD_DIM];
    __shared__ float sc[GROUP][CHUNK];
    __shared__ float red[4][GROUP][HEAD_DIM];
    __shared__ float mls[GROUP][2];

    const int tid  = threadIdx.x;
    const int wave = tid >> 6;
    const int lane = tid & 63;

    for (int idx = tid; idx < GROUP * HEAD_DIM; idx += 256) {
        int g = idx >> 7, d = idx & 127;
        qs[g][d] = qkv[(size_t)s * QKV_OUT + (h * GROUP + g) * HEAD_DIM + d];
    }
    __syncthreads();

    const int*   bt   = block_tables + s * BLOCKS_PER_SEQ;
    const float* knew = qkv + (size_t)s * QKV_OUT + Q_SIZE + h * HEAD_DIM;
    const float* vnew = qkv + (size_t)s * QKV_OUT + Q_SIZE + KV_SIZE + h * HEAD_DIM;

    // ---- phase 1: one token per lane ----
    {
        const int t = c * CHUNK + tid;
        const float* kp;
        if (t == pos) kp = knew;
        else {
            int blk = bt[t >> 4];
            kp = k_cache + ((size_t)(blk * BLK_SZ + (t & 15)) * N_KV + h) * HEAD_DIM;
        }
        float s0 = 0.f, s1 = 0.f, s2 = 0.f, s3 = 0.f;
        #pragma unroll 8
        for (int d4 = 0; d4 < 32; ++d4) {
            float4 kv = *(const float4*)(kp + d4 * 4);
            float4 q0 = *(const float4*)(&qs[0][d4 * 4]);
            float4 q1 = *(const float4*)(&qs[1][d4 * 4]);
            float4 q2 = *(const float4*)(&qs[2][d4 * 4]);
            float4 q3 = *(const float4*)(&qs[3][d4 * 4]);
            s0 = fmaf(kv.x,q0.x, fmaf(kv.y,q0.y, fmaf(kv.z,q0.z, fmaf(kv.w,q0.w, s0))));
            s1 = fmaf(kv.x,q1.x, fmaf(kv.y,q1.y, fmaf(kv.z,q1.z, fmaf(kv.w,q1.w, s1))));
            s2 = fmaf(kv.x,q2.x, fmaf(kv.y,q2.y, fmaf(kv.z,q2.z, fmaf(kv.w,q2.w, s2))));
            s3 = fmaf(kv.x,q3.x, fmaf(kv.y,q3.y, fmaf(kv.z,q3.z, fmaf(kv.w,q3.w, s3))));
        }
        if (tid < nvalid) {
            sc[0][tid] = s0 * ATT_SCALE; sc[1][tid] = s1 * ATT_SCALE;
            sc[2][tid] = s2 * ATT_SCALE; sc[3][tid] = s3 * ATT_SCALE;
        } else {
            sc[0][tid] = -1e30f; sc[1][tid] = -1e30f;
            sc[2][tid] = -1e30f; sc[3][tid] = -1e30f;
        }
    }
    __syncthreads();

    // ---- chunk-local softmax: wave g owns head g ----
    {
        const int g = wave;
        float m = -1e30f;
        #pragma unroll
        for (int r = 0; r < 4; ++r) m = fmaxf(m, sc[g][lane + r * 64]);
        #pragma unroll
        for (int off = 32; off; off >>= 1) m = fmaxf(m, __shfl_xor(m, off));
        float l = 0.f;
        #pragma unroll
        for (int r = 0; r < 4; ++r) {
            float e = __expf(sc[g][lane + r * 64] - m);
            sc[g][lane + r * 64] = e;
            l += e;
        }
        #pragma unroll
        for (int off = 32; off; off >>= 1) l += __shfl_xor(l, off);
        if (lane == 0) { mls[g][0] = m; mls[g][1] = l; }
    }
    __syncthreads();

    // ---- phase 2: PV, wave handles 64 consecutive tokens, coalesced V ----
    float2 acc[GROUP] = {};
    int cnt = nvalid - wave * 64;
    if (cnt > 64) cnt = 64;
    for (int ii = 0; ii < cnt; ++ii) {
        const int i = wave * 64 + ii;
        const int t = c * CHUNK + i;
        const float* vp;
        if (t == pos) vp = vnew;
        else {
            int blk = bt[t >> 4];
            vp = v_cache + ((size_t)(blk * BLK_SZ + (t & 15)) * N_KV + h) * HEAD_DIM;
        }
        float2 vv = *(const float2*)(vp + lane * 2);
        #pragma unroll
        for (int g = 0; g < GROUP; ++g) {
            float p = sc[g][i];
            acc[g].x = fmaf(p, vv.x, acc[g].x);
            acc[g].y = fmaf(p, vv.y, acc[g].y);
        }
    }
    #pragma unroll
    for (int g = 0; g < GROUP; ++g) {
        red[wave][g][lane*2]   = acc[g].x;
        red[wave][g][lane*2+1] = acc[g].y;
    }
    __syncthreads();

    {
        const int g = wave;
        float ox = red[0][g][lane*2]   + red[1][g][lane*2]   + red[2][g][lane*2]   + red[3][g][lane*2];
        float oy = red[0][g][lane*2+1] + red[1][g][lane*2+1] + red[2][g][lane*2+1] + red[3][g][lane*2+1];
        size_t idx = ((size_t)sh * NCHUNK + c) * GROUP + g;
        pacc[idx * HEAD_DIM + lane*2]     = ox;
        pacc[idx * HEAD_DIM + lane*2 + 1] = oy;
        if (lane == 0) { pml[idx*2] = mls[g][0]; pml[idx*2+1] = mls[g][1]; }
    }
}

// ---------------- combine chunk partials ----------------
__global__ __launch_bounds__(256)
void attn_reduce(const float* __restrict__ pacc, const float* __restrict__ pml,
                 const int* __restrict__ context_lens, float* __restrict__ out) {
    const int sh = blockIdx.x;
    const int s  = sh >> 3;
    const int h  = sh & 7;
    const int g    = threadIdx.x >> 6;
    const int lane = threadIdx.x & 63;
    const int ctx = context_lens[s];
    const int nc  = (ctx + CHUNK - 1) / CHUNK;

    float M = -1e30f;
    for (int cc = 0; cc < nc; ++cc)
        M = fmaxf(M, pml[(((size_t)sh * NCHUNK + cc) * GROUP + g) * 2]);
    float ox = 0.f, oy = 0.f, L = 0.f;
    for (int cc = 0; cc < nc; ++cc) {
        size_t idx = ((size_t)sh * NCHUNK + cc) * GROUP + g;
        float w = __expf(pml[idx*2] - M);
        L = fmaf(w, pml[idx*2+1], L);
        float2 pa = *(const float2*)(pacc + idx * HEAD_DIM + lane*2);
        ox = fmaf(w, pa.x, ox);
        oy = fmaf(w, pa.y, oy);
    }
    float inv = 1.0f / L;
    float* op = out + (size_t)s * Q_SIZE + (h * GROUP + g) * HEAD_DIM;
    op[lane*2]     = ox * inv;
    op[lane*2 + 1] = oy * inv;
}

extern "C" void kernel_launch(void* const* d_in, const int* in_sizes, int n_in,
                              void* d_out, int out_size, void* d_ws, size_t ws_size,
                              hipStream_t stream) {
    const int*   positions    = (const int*)  d_in[0];
    const float* hidden       = (const float*)d_in[1];
    const float* k_cache      = (const float*)d_in[2];
    const float* v_cache      = (const float*)d_in[3];
    const int*   block_tables = (const int*)  d_in[4];
    const int*   context_lens = (const int*)  d_in[5];
    const float* W_qkv        = (const float*)d_in[6];
    const float* W_o          = (const float*)d_in[7];
    float* out = (float*)d_out;

    float* qkv_ws  = (float*)d_ws;                                   // 393216 f
    float* attn_ws = qkv_ws + (size_t)NUM_SEQS * QKV_OUT;            // 262144 f
    float* scratch = attn_ws + (size_t)NUM_SEQS * Q_SIZE;
    // scratch reused sequentially: QKV partials (8*393216 f) -> attn pacc/pml -> O partials
    float* pacc = scratch;                                            // 2097152 f
    float* pml  = scratch + (size_t)NUM_SEQS * N_KV * NCHUNK * GROUP * HEAD_DIM; // 32768 f

    // 1) QKV projection (MFMA, K-split partials) + fused reduce+RoPE
    gemm_mfma<<<dim3(QKV_OUT / 64, KSPLIT), 256, 0, stream>>>(hidden, W_qkv, scratch, QKV_OUT);
    qkv_reduce_rope<<<dim3(NUM_SEQS, 14), 256, 0, stream>>>(scratch, qkv_ws, positions);
    // 2) flash-decode attention
    attn_chunk<<<dim3(NUM_SEQS * N_KV, NCHUNK), 256, 0, stream>>>(
        qkv_ws, k_cache, v_cache, block_tables, context_lens, pacc, pml);
    attn_reduce<<<NUM_SEQS * N_KV, 256, 0, stream>>>(pacc, pml, context_lens, attn_ws);
    // 3) output projection (MFMA, K-split partials) + reduce
    gemm_mfma<<<dim3(Q_SIZE / 64, KSPLIT), 256, 0, stream>>>(attn_ws, W_o, scratch, Q_SIZE);
    reduce_ksplit<<<(NUM_SEQS * Q_SIZE + 255) / 256, 256, 0, stream>>>(scratch, out, NUM_SEQS * Q_SIZE);
}

// Round 4
// 257.264 us; speedup vs baseline: 7.6616x; 1.1179x over previous
//
#include <hip/hip_runtime.h>
#include <math.h>

#define H_SIZE   4096
#define N_HEADS  32
#define N_KV     8
#define HEAD_DIM 128
#define GROUP    4
#define Q_SIZE   4096
#define KV_SIZE  1024
#define QKV_OUT  6144          // Q_SIZE + 2*KV_SIZE
#define NUM_SEQS 64
#define MAX_CTX  2048
#define BLK_SZ   16
#define BLOCKS_PER_SEQ 128
#define ATT_SCALE 0.08838834764831845f   // 128^-0.5

#define CHUNK    256
#define NCHUNK   8             // MAX_CTX / CHUNK
#define KSPLIT   8
#define KCHUNK   512           // H_SIZE / KSPLIT

typedef __attribute__((ext_vector_type(8))) short bf16x8;
typedef __attribute__((ext_vector_type(4))) float f32x4;

__device__ __forceinline__ short f2bf(float f) {
    return __builtin_bit_cast(short, (__bf16)f);   // compiler emits v_cvt_pk_bf16_f32
}

__device__ __forceinline__ bf16x8 cvt8(float4 a, float4 b) {
    bf16x8 r;
    r[0]=f2bf(a.x); r[1]=f2bf(a.y); r[2]=f2bf(a.z); r[3]=f2bf(a.w);
    r[4]=f2bf(b.x); r[5]=f2bf(b.y); r[6]=f2bf(b.z); r[7]=f2bf(b.w);
    return r;
}

// ---------------- fp32 -> bf16 bulk convert (X operand, done once) ----------------
__global__ __launch_bounds__(256)
void cvt_bf16(const float* __restrict__ in, unsigned short* __restrict__ out, int n4) {
    int i = blockIdx.x * 256 + threadIdx.x;
    if (i >= n4) return;
    float4 v = *(const float4*)(in + (size_t)i * 4);
    ushort2 lo = { (unsigned short)(unsigned)(unsigned short)f2bf(v.x),
                   (unsigned short)(unsigned)(unsigned short)f2bf(v.y) };
    ushort2 hi = { (unsigned short)(unsigned)(unsigned short)f2bf(v.z),
                   (unsigned short)(unsigned)(unsigned short)f2bf(v.w) };
    *(ushort2*)(out + (size_t)i * 4)     = lo;
    *(ushort2*)(out + (size_t)i * 4 + 2) = hi;
}

// ---------------- MFMA GEMM: Yp[c][64][N] = A[64][4096] @ W[N][4096]^T ----------
// A pre-converted bf16 (L2-hot); W fp32 streamed once, cvt in regs.
// grid (N/64, KSPLIT); block 256 = 4 waves; wave w owns cols n0+w*16..+15.
__global__ __launch_bounds__(256)
void gemm_mfma(const unsigned short* __restrict__ A, const float* __restrict__ W,
               float* __restrict__ Yp, int N) {
    const int n0   = blockIdx.x * 64;
    const int k0   = blockIdx.y * KCHUNK;
    const int wave = threadIdx.x >> 6;
    const int lane = threadIdx.x & 63;
    const int ncol = n0 + wave * 16 + (lane & 15);
    const int klane = (lane >> 4) * 8;

    const float*          wrow = W + (size_t)ncol * H_SIZE + k0 + klane;
    const unsigned short* arow = A + (size_t)(lane & 15) * H_SIZE + k0 + klane;

    f32x4 acc[4] = {};
    for (int k = 0; k < KCHUNK; k += 32) {
        float4 wa = *(const float4*)(wrow + k);
        float4 wb = *(const float4*)(wrow + k + 4);
        bf16x8 bf = cvt8(wa, wb);
        #pragma unroll
        for (int m = 0; m < 4; ++m) {
            bf16x8 af = *(const bf16x8*)(const void*)(arow + (size_t)m * 16 * H_SIZE + k);
            acc[m] = __builtin_amdgcn_mfma_f32_16x16x32_bf16(af, bf, acc[m], 0, 0, 0);
        }
    }
    float* yp = Yp + (size_t)blockIdx.y * 64 * N;
    #pragma unroll
    for (int m = 0; m < 4; ++m)
        #pragma unroll
        for (int j = 0; j < 4; ++j)
            yp[(size_t)(m * 16 + (lane >> 4) * 4 + j) * N + ncol] = acc[m][j];
}

// ---------------- fused K-split reduce + RoPE for QKV ----------------
__global__ __launch_bounds__(256)
void qkv_reduce_rope(const float* __restrict__ Yp, float* __restrict__ qkv,
                     const int* __restrict__ positions) {
    const int s   = blockIdx.x;
    const int idx = blockIdx.y * 256 + threadIdx.x;
    const float pos = (float)positions[s];
    if (idx < 2560) {
        const int head = idx >> 6, d = idx & 63;
        const int j1 = (head < N_HEADS ? head * HEAD_DIM
                                       : Q_SIZE + (head - N_HEADS) * HEAD_DIM) + d;
        const int j2 = j1 + 64;
        float x1 = 0.f, x2 = 0.f;
        #pragma unroll
        for (int c = 0; c < KSPLIT; ++c) {
            x1 += Yp[((size_t)c * 64 + s) * QKV_OUT + j1];
            x2 += Yp[((size_t)c * 64 + s) * QKV_OUT + j2];
        }
        const float inv_freq = powf(10000.0f, -(float)d / 64.0f);
        const float ang = pos * inv_freq;
        const float cs = cosf(ang), sn = sinf(ang);
        qkv[(size_t)s * QKV_OUT + j1] = x1 * cs - x2 * sn;
        qkv[(size_t)s * QKV_OUT + j2] = x2 * cs + x1 * sn;
    } else if (idx < 3584) {
        const int j = Q_SIZE + KV_SIZE + (idx - 2560);
        float v = 0.f;
        #pragma unroll
        for (int c = 0; c < KSPLIT; ++c)
            v += Yp[((size_t)c * 64 + s) * QKV_OUT + j];
        qkv[(size_t)s * QKV_OUT + j] = v;
    }
}

__global__ __launch_bounds__(256)
void reduce_ksplit(const float* __restrict__ Yp, float* __restrict__ Y, int total) {
    int i = blockIdx.x * 256 + threadIdx.x;
    if (i >= total) return;
    float s = 0.f;
    #pragma unroll
    for (int c = 0; c < KSPLIT; ++c) s += Yp[(size_t)c * total + i];
    Y[i] = s;
}

// ---------------- Flash-decode attention: per-chunk partials ----------------
// Phase 1: 4 lanes per token -> 128B contiguous per lane, 16 full lines/instr.
__global__ __launch_bounds__(256)
void attn_chunk(const float* __restrict__ qkv,
                const float* __restrict__ k_cache,
                const float* __restrict__ v_cache,
                const int*   __restrict__ block_tables,
                const int*   __restrict__ context_lens,
                float* __restrict__ pacc,   // [sh][c][g][128]
                float* __restrict__ pml) {  // [sh][c][g][2]
    const int sh = blockIdx.x;
    const int s  = sh >> 3;
    const int h  = sh & 7;
    const int c  = blockIdx.y;
    const int ctx = context_lens[s];
    if (c * CHUNK >= ctx) return;
    const int pos = ctx - 1;
    const int nvalid = min(CHUNK, ctx - c * CHUNK);

    __shared__ float qs2[GROUP][4][36];      // padded quarter-rows: conflict-free
    __shared__ float sc[GROUP][CHUNK];
    __shared__ float red[4][GROUP][HEAD_DIM];
    __shared__ float mls[GROUP][2];

    const int tid  = threadIdx.x;
    const int wave = tid >> 6;
    const int lane = tid & 63;

    for (int idx = tid; idx < GROUP * HEAD_DIM; idx += 256) {
        int g = idx >> 7, d = idx & 127;
        qs2[g][d >> 5][d & 31] = qkv[(size_t)s * QKV_OUT + (h * GROUP + g) * HEAD_DIM + d];
    }
    __syncthreads();

    const int*   bt   = block_tables + s * BLOCKS_PER_SEQ;
    const float* knew = qkv + (size_t)s * QKV_OUT + Q_SIZE + h * HEAD_DIM;
    const float* vnew = qkv + (size_t)s * QKV_OUT + Q_SIZE + KV_SIZE + h * HEAD_DIM;

    // ---- phase 1: scores, quad-per-token ----
    {
        const int sub = lane & 3;
        const int tip = lane >> 2;        // 0..15
        #pragma unroll
        for (int pass = 0; pass < 4; ++pass) {
            const int i = wave * 64 + pass * 16 + tip;
            const int t = c * CHUNK + i;
            float s0 = 0.f, s1 = 0.f, s2 = 0.f, s3 = 0.f;
            if (i < nvalid) {
                const float* kp;
                if (t == pos) kp = knew;
                else {
                    int blk = bt[t >> 4];
                    kp = k_cache + ((size_t)(blk * BLK_SZ + (t & 15)) * N_KV + h) * HEAD_DIM;
                }
                kp += sub * 32;
                #pragma unroll
                for (int d4 = 0; d4 < 8; ++d4) {
                    float4 kv = *(const float4*)(kp + d4 * 4);
                    float4 q0 = *(const float4*)(&qs2[0][sub][d4 * 4]);
                    float4 q1 = *(const float4*)(&qs2[1][sub][d4 * 4]);
                    float4 q2 = *(const float4*)(&qs2[2][sub][d4 * 4]);
                    float4 q3 = *(const float4*)(&qs2[3][sub][d4 * 4]);
                    s0 = fmaf(kv.x,q0.x, fmaf(kv.y,q0.y, fmaf(kv.z,q0.z, fmaf(kv.w,q0.w, s0))));
                    s1 = fmaf(kv.x,q1.x, fmaf(kv.y,q1.y, fmaf(kv.z,q1.z, fmaf(kv.w,q1.w, s1))));
                    s2 = fmaf(kv.x,q2.x, fmaf(kv.y,q2.y, fmaf(kv.z,q2.z, fmaf(kv.w,q2.w, s2))));
                    s3 = fmaf(kv.x,q3.x, fmaf(kv.y,q3.y, fmaf(kv.z,q3.z, fmaf(kv.w,q3.w, s3))));
                }
            }
            s0 += __shfl_xor(s0, 1); s0 += __shfl_xor(s0, 2);
            s1 += __shfl_xor(s1, 1); s1 += __shfl_xor(s1, 2);
            s2 += __shfl_xor(s2, 1); s2 += __shfl_xor(s2, 2);
            s3 += __shfl_xor(s3, 1); s3 += __shfl_xor(s3, 2);
            if (sub == 0) {
                const bool v = (i < nvalid);
                sc[0][i] = v ? s0 * ATT_SCALE : -1e30f;
                sc[1][i] = v ? s1 * ATT_SCALE : -1e30f;
                sc[2][i] = v ? s2 * ATT_SCALE : -1e30f;
                sc[3][i] = v ? s3 * ATT_SCALE : -1e30f;
            }
        }
    }
    __syncthreads();

    // ---- chunk-local softmax: wave g owns head g ----
    {
        const int g = wave;
        float m = -1e30f;
        #pragma unroll
        for (int r = 0; r < 4; ++r) m = fmaxf(m, sc[g][lane + r * 64]);
        #pragma unroll
        for (int off = 32; off; off >>= 1) m = fmaxf(m, __shfl_xor(m, off));
        float l = 0.f;
        #pragma unroll
        for (int r = 0; r < 4; ++r) {
            float e = __expf(sc[g][lane + r * 64] - m);
            sc[g][lane + r * 64] = e;
            l += e;
        }
        #pragma unroll
        for (int off = 32; off; off >>= 1) l += __shfl_xor(l, off);
        if (lane == 0) { mls[g][0] = m; mls[g][1] = l; }
    }
    __syncthreads();

    // ---- phase 2: PV, coalesced float2 V rows ----
    float2 acc[GROUP] = {};
    int cnt = nvalid - wave * 64;
    if (cnt > 64) cnt = 64;
    #pragma unroll 2
    for (int ii = 0; ii < cnt; ++ii) {
        const int i = wave * 64 + ii;
        const int t = c * CHUNK + i;
        const float* vp;
        if (t == pos) vp = vnew;
        else {
            int blk = bt[t >> 4];
            vp = v_cache + ((size_t)(blk * BLK_SZ + (t & 15)) * N_KV + h) * HEAD_DIM;
        }
        float2 vv = *(const float2*)(vp + lane * 2);
        #pragma unroll
        for (int g = 0; g < GROUP; ++g) {
            float p = sc[g][i];
            acc[g].x = fmaf(p, vv.x, acc[g].x);
            acc[g].y = fmaf(p, vv.y, acc[g].y);
        }
    }
    #pragma unroll
    for (int g = 0; g < GROUP; ++g) {
        red[wave][g][lane*2]   = acc[g].x;
        red[wave][g][lane*2+1] = acc[g].y;
    }
    __syncthreads();

    {
        const int g = wave;
        float ox = red[0][g][lane*2]   + red[1][g][lane*2]   + red[2][g][lane*2]   + red[3][g][lane*2];
        float oy = red[0][g][lane*2+1] + red[1][g][lane*2+1] + red[2][g][lane*2+1] + red[3][g][lane*2+1];
        size_t idx = ((size_t)sh * NCHUNK + c) * GROUP + g;
        pacc[idx * HEAD_DIM + lane*2]     = ox;
        pacc[idx * HEAD_DIM + lane*2 + 1] = oy;
        if (lane == 0) { pml[idx*2] = mls[g][0]; pml[idx*2+1] = mls[g][1]; }
    }
}

// ---------------- combine chunk partials; emit bf16 for the O-GEMM ----------------
__global__ __launch_bounds__(256)
void attn_reduce(const float* __restrict__ pacc, const float* __restrict__ pml,
                 const int* __restrict__ context_lens, unsigned short* __restrict__ outbf) {
    const int sh = blockIdx.x;
    const int s  = sh >> 3;
    const int h  = sh & 7;
    const int g    = threadIdx.x >> 6;
    const int lane = threadIdx.x & 63;
    const int ctx = context_lens[s];
    const int nc  = (ctx + CHUNK - 1) / CHUNK;

    float M = -1e30f;
    for (int cc = 0; cc < nc; ++cc)
        M = fmaxf(M, pml[(((size_t)sh * NCHUNK + cc) * GROUP + g) * 2]);
    float ox = 0.f, oy = 0.f, L = 0.f;
    for (int cc = 0; cc < nc; ++cc) {
        size_t idx = ((size_t)sh * NCHUNK + cc) * GROUP + g;
        float w = __expf(pml[idx*2] - M);
        L = fmaf(w, pml[idx*2+1], L);
        float2 pa = *(const float2*)(pacc + idx * HEAD_DIM + lane*2);
        ox = fmaf(w, pa.x, ox);
        oy = fmaf(w, pa.y, oy);
    }
    float inv = 1.0f / L;
    unsigned short* op = outbf + (size_t)s * Q_SIZE + (h * GROUP + g) * HEAD_DIM;
    ushort2 o2 = { (unsigned short)f2bf(ox * inv), (unsigned short)f2bf(oy * inv) };
    *(ushort2*)(op + lane * 2) = o2;
}

extern "C" void kernel_launch(void* const* d_in, const int* in_sizes, int n_in,
                              void* d_out, int out_size, void* d_ws, size_t ws_size,
                              hipStream_t stream) {
    const int*   positions    = (const int*)  d_in[0];
    const float* hidden       = (const float*)d_in[1];
    const float* k_cache      = (const float*)d_in[2];
    const float* v_cache      = (const float*)d_in[3];
    const int*   block_tables = (const int*)  d_in[4];
    const int*   context_lens = (const int*)  d_in[5];
    const float* W_qkv        = (const float*)d_in[6];
    const float* W_o          = (const float*)d_in[7];
    float* out = (float*)d_out;

    float* qkv_ws = (float*)d_ws;                                     // 393216 f
    unsigned short* hidden_bf = (unsigned short*)(qkv_ws + (size_t)NUM_SEQS * QKV_OUT); // 262144 us = 131072 f
    unsigned short* attn_bf   = hidden_bf + (size_t)NUM_SEQS * H_SIZE;                  // 262144 us
    float* scratch = (float*)(attn_bf + (size_t)NUM_SEQS * H_SIZE);
    // scratch reused: QKV partials (8*393216 f) -> attn pacc/pml -> O partials
    float* pacc = scratch;
    float* pml  = scratch + (size_t)NUM_SEQS * N_KV * NCHUNK * GROUP * HEAD_DIM;

    // 0) X -> bf16 (once)
    cvt_bf16<<<(NUM_SEQS * H_SIZE / 4 + 255) / 256, 256, 0, stream>>>(
        hidden, hidden_bf, NUM_SEQS * H_SIZE / 4);
    // 1) QKV projection + fused reduce+RoPE
    gemm_mfma<<<dim3(QKV_OUT / 64, KSPLIT), 256, 0, stream>>>(hidden_bf, W_qkv, scratch, QKV_OUT);
    qkv_reduce_rope<<<dim3(NUM_SEQS, 14), 256, 0, stream>>>(scratch, qkv_ws, positions);
    // 2) flash-decode attention
    attn_chunk<<<dim3(NUM_SEQS * N_KV, NCHUNK), 256, 0, stream>>>(
        qkv_ws, k_cache, v_cache, block_tables, context_lens, pacc, pml);
    attn_reduce<<<NUM_SEQS * N_KV, 256, 0, stream>>>(pacc, pml, context_lens, attn_bf);
    // 3) output projection + reduce
    gemm_mfma<<<dim3(Q_SIZE / 64, KSPLIT), 256, 0, stream>>>(attn_bf, W_o, scratch, Q_SIZE);
    reduce_ksplit<<<(NUM_SEQS * Q_SIZE + 255) / 256, 256, 0, stream>>>(scratch, out, NUM_SEQS * Q_SIZE);
}